// Round 2
// baseline (431.701 us; speedup 1.0000x reference)
//
#include <hip/hip_runtime.h>
#include <cstdint>
#include <cstddef>

typedef unsigned short u16;
typedef __bf16 bf16x8 __attribute__((ext_vector_type(8)));
typedef u16 u16x8 __attribute__((ext_vector_type(8)));
typedef float f32x4 __attribute__((ext_vector_type(4)));

#define N_NODES 100000
#define SAMPLE 25
#define FEAT 128
#define CLASSES 40
#define NPB 64            // nodes per block
#define AGG_STRIDE 136    // 128 + 8 u16 pad

__device__ __forceinline__ float bf2f(u16 v) {
    return __uint_as_float(((unsigned)v) << 16);
}
__device__ __forceinline__ u16 f2bf(float f) {
    unsigned u = __float_as_uint(f);
    u += 0x7FFFu + ((u >> 16) & 1u);
    return (u16)(u >> 16);
}
__device__ __forceinline__ void split_bf(float x, u16& hi, u16& lo) {
    hi = f2bf(x);
    lo = f2bf(x - bf2f(hi));
}

// ---------------------------------------------------------------------------
// Prep: split fp32 weights into bf16 hi/lo pairs (same row-major layout)
// ---------------------------------------------------------------------------
__global__ __launch_bounds__(256) void prep_weights(
    const float* __restrict__ W1, const float* __restrict__ W2,
    const float* __restrict__ Wl,
    u16* __restrict__ w1h, u16* __restrict__ w1l,
    u16* __restrict__ w2h, u16* __restrict__ w2l,
    u16* __restrict__ wlh, u16* __restrict__ wll)
{
    const int i = blockIdx.x * 256 + threadIdx.x;
    const int stride = gridDim.x * 256;
    for (int j = i; j < FEAT * FEAT; j += stride) {
        split_bf(W1[j], w1h[j], w1l[j]);
        split_bf(W2[j], w2h[j], w2l[j]);
    }
    for (int j = i; j < CLASSES * FEAT; j += stride) {
        split_bf(Wl[j], wlh[j], wll[j]);
    }
}

// shared MFMA helper: 3-product split GEMM accumulate over one 32-wide K block
__device__ __forceinline__ f32x4 mfma_split(bf16x8 ah, bf16x8 al,
                                            bf16x8 bh, bf16x8 bl, f32x4 acc) {
    acc = __builtin_amdgcn_mfma_f32_16x16x32_bf16(ah, bh, acc, 0, 0, 0);
    acc = __builtin_amdgcn_mfma_f32_16x16x32_bf16(al, bh, acc, 0, 0, 0);
    acc = __builtin_amdgcn_mfma_f32_16x16x32_bf16(ah, bl, acc, 0, 0, 0);
    return acc;
}

// ---------------------------------------------------------------------------
// Layer 1: h1[n] = relu( mean_s X[nb[n][s]] @ W1^T )   (X fp32, h1 bf16)
// ---------------------------------------------------------------------------
__global__ __launch_bounds__(256) void gnn_layer1(
    const float* __restrict__ X, const int* __restrict__ nb,
    const u16* __restrict__ w1h, const u16* __restrict__ w1l,
    u16* __restrict__ h1)
{
    __shared__ int nbs[NPB * SAMPLE];
    __shared__ u16 agg_h[NPB][AGG_STRIDE];
    __shared__ u16 agg_l[NPB][AGG_STRIDE];

    const int t = threadIdx.x;
    const int blockStart = blockIdx.x * NPB;

    for (int i = t; i < NPB * SAMPLE; i += 256) {
        int gi = blockStart * SAMPLE + i;
        if (gi >= N_NODES * SAMPLE) gi = N_NODES * SAMPLE - 1;
        nbs[i] = nb[gi];
    }
    __syncthreads();

    // gather + mean (fp32), split to bf16 hi/lo LDS tiles
    for (int item = t; item < NPB * 16; item += 256) {
        const int nl = item >> 4;
        const int fg = item & 15;
        float acc[8];
        #pragma unroll
        for (int j = 0; j < 8; ++j) acc[j] = 0.f;
        const int* myn = &nbs[nl * SAMPLE];
        for (int s = 0; s < SAMPLE; ++s) {
            const float4* p = (const float4*)(X + (size_t)myn[s] * FEAT + fg * 8);
            float4 a = p[0], b = p[1];
            acc[0] += a.x; acc[1] += a.y; acc[2] += a.z; acc[3] += a.w;
            acc[4] += b.x; acc[5] += b.y; acc[6] += b.z; acc[7] += b.w;
        }
        u16x8 oh, ol;
        #pragma unroll
        for (int j = 0; j < 8; ++j) {
            float m = acc[j] * (1.0f / SAMPLE);
            u16 h, l; split_bf(m, h, l);
            oh[j] = h; ol[j] = l;
        }
        *(u16x8*)&agg_h[nl][fg * 8] = oh;
        *(u16x8*)&agg_l[nl][fg * 8] = ol;
    }
    __syncthreads();

    const int w  = t >> 6;
    const int l  = t & 63;
    const int lr = l & 15;
    const int lq = l >> 4;

    bf16x8 ah[4], al[4];
    #pragma unroll
    for (int k = 0; k < 4; ++k) {
        ah[k] = *(const bf16x8*)&agg_h[w * 16 + lr][k * 32 + lq * 8];
        al[k] = *(const bf16x8*)&agg_l[w * 16 + lr][k * 32 + lq * 8];
    }

    #pragma unroll
    for (int c = 0; c < 8; ++c) {
        f32x4 acc = {0.f, 0.f, 0.f, 0.f};
        #pragma unroll
        for (int k = 0; k < 4; ++k) {
            const size_t off = (size_t)(c * 16 + lr) * FEAT + k * 32 + lq * 8;
            bf16x8 bh = *(const bf16x8*)(w1h + off);
            bf16x8 bl = *(const bf16x8*)(w1l + off);
            acc = mfma_split(ah[k], al[k], bh, bl, acc);
        }
        #pragma unroll
        for (int r = 0; r < 4; ++r) {
            int node = blockStart + w * 16 + lq * 4 + r;
            if (node < N_NODES) {
                float v = acc[r] > 0.f ? acc[r] : 0.f;
                h1[(size_t)node * FEAT + c * 16 + lr] = f2bf(v);
            }
        }
    }
}

// ---------------------------------------------------------------------------
// Layer 2 + final: h2 = relu( mean_s h1[nb[n][s]] @ W2^T ) (LDS, hi/lo),
//                  out = h2 @ Wlast^T  (fp32 out)
// ---------------------------------------------------------------------------
__global__ __launch_bounds__(256) void gnn_layer2_final(
    const u16* __restrict__ h1, const int* __restrict__ nb,
    const u16* __restrict__ w2h, const u16* __restrict__ w2l,
    const u16* __restrict__ wlh, const u16* __restrict__ wll,
    float* __restrict__ out)
{
    __shared__ int nbs[NPB * SAMPLE];
    __shared__ u16 agg_h[NPB][AGG_STRIDE];
    __shared__ u16 agg_l[NPB][AGG_STRIDE];

    const int t = threadIdx.x;
    const int blockStart = blockIdx.x * NPB;

    for (int i = t; i < NPB * SAMPLE; i += 256) {
        int gi = blockStart * SAMPLE + i;
        if (gi >= N_NODES * SAMPLE) gi = N_NODES * SAMPLE - 1;
        nbs[i] = nb[gi];
    }
    __syncthreads();

    // gather h1 (bf16) + mean in fp32, split hi/lo
    for (int item = t; item < NPB * 16; item += 256) {
        const int nl = item >> 4;
        const int fg = item & 15;
        float acc[8];
        #pragma unroll
        for (int j = 0; j < 8; ++j) acc[j] = 0.f;
        const int* myn = &nbs[nl * SAMPLE];
        for (int s = 0; s < SAMPLE; ++s) {
            u16x8 v = *(const u16x8*)(h1 + (size_t)myn[s] * FEAT + fg * 8);
            #pragma unroll
            for (int j = 0; j < 8; ++j) acc[j] += bf2f(v[j]);
        }
        u16x8 oh, ol;
        #pragma unroll
        for (int j = 0; j < 8; ++j) {
            float m = acc[j] * (1.0f / SAMPLE);
            u16 h, l; split_bf(m, h, l);
            oh[j] = h; ol[j] = l;
        }
        *(u16x8*)&agg_h[nl][fg * 8] = oh;
        *(u16x8*)&agg_l[nl][fg * 8] = ol;
    }
    __syncthreads();

    const int w  = t >> 6;
    const int l  = t & 63;
    const int lr = l & 15;
    const int lq = l >> 4;

    // W2 GEMM into registers for all 8 column tiles
    f32x4 hacc[8];
    {
        bf16x8 ah[4], al[4];
        #pragma unroll
        for (int k = 0; k < 4; ++k) {
            ah[k] = *(const bf16x8*)&agg_h[w * 16 + lr][k * 32 + lq * 8];
            al[k] = *(const bf16x8*)&agg_l[w * 16 + lr][k * 32 + lq * 8];
        }
        #pragma unroll
        for (int c = 0; c < 8; ++c) {
            f32x4 acc = {0.f, 0.f, 0.f, 0.f};
            #pragma unroll
            for (int k = 0; k < 4; ++k) {
                const size_t off = (size_t)(c * 16 + lr) * FEAT + k * 32 + lq * 8;
                bf16x8 bh = *(const bf16x8*)(w2h + off);
                bf16x8 bl = *(const bf16x8*)(w2l + off);
                acc = mfma_split(ah[k], al[k], bh, bl, acc);
            }
            hacc[c] = acc;
        }
    }
    __syncthreads();   // everyone finished reading agg tiles

    // relu + split h2 into the (reused) agg tiles
    #pragma unroll
    for (int c = 0; c < 8; ++c) {
        #pragma unroll
        for (int r = 0; r < 4; ++r) {
            float v = hacc[c][r] > 0.f ? hacc[c][r] : 0.f;
            u16 h, l2; split_bf(v, h, l2);
            agg_h[w * 16 + lq * 4 + r][c * 16 + lr] = h;
            agg_l[w * 16 + lq * 4 + r][c * 16 + lr] = l2;
        }
    }
    __syncthreads();

    // final projection: out = h2 @ Wlast^T (3 column tiles covering 48, guard 40)
    {
        bf16x8 ah[4], al[4];
        #pragma unroll
        for (int k = 0; k < 4; ++k) {
            ah[k] = *(const bf16x8*)&agg_h[w * 16 + lr][k * 32 + lq * 8];
            al[k] = *(const bf16x8*)&agg_l[w * 16 + lr][k * 32 + lq * 8];
        }
        #pragma unroll
        for (int c = 0; c < 3; ++c) {
            const int o = c * 16 + lr;
            f32x4 acc = {0.f, 0.f, 0.f, 0.f};
            #pragma unroll
            for (int k = 0; k < 4; ++k) {
                bf16x8 bh, bl;
                if (o < CLASSES) {
                    const size_t off = (size_t)o * FEAT + k * 32 + lq * 8;
                    bh = *(const bf16x8*)(wlh + off);
                    bl = *(const bf16x8*)(wll + off);
                } else {
                    #pragma unroll
                    for (int j = 0; j < 8; ++j) { bh[j] = (__bf16)0.f; bl[j] = (__bf16)0.f; }
                }
                acc = mfma_split(ah[k], al[k], bh, bl, acc);
            }
            if (o < CLASSES) {
                #pragma unroll
                for (int r = 0; r < 4; ++r) {
                    int node = blockStart + w * 16 + lq * 4 + r;
                    if (node < N_NODES) {
                        out[(size_t)node * CLASSES + o] = acc[r];
                    }
                }
            }
        }
    }
}

extern "C" void kernel_launch(void* const* d_in, const int* in_sizes, int n_in,
                              void* d_out, int out_size, void* d_ws, size_t ws_size,
                              hipStream_t stream) {
    const float* X  = (const float*)d_in[0];
    const int*   nb = (const int*)d_in[1];
    const float* W1 = (const float*)d_in[2];
    const float* W2 = (const float*)d_in[3];
    const float* Wl = (const float*)d_in[4];
    float* out = (float*)d_out;

    // ws layout: h1 (bf16, 25.6 MB) | weight hi/lo splits
    u16* h1  = (u16*)d_ws;
    char* wp = (char*)d_ws + (size_t)N_NODES * FEAT * sizeof(u16);
    u16* w1h = (u16*)(wp);
    u16* w1l = w1h + FEAT * FEAT;
    u16* w2h = w1l + FEAT * FEAT;
    u16* w2l = w2h + FEAT * FEAT;
    u16* wlh = w2l + FEAT * FEAT;
    u16* wll = wlh + CLASSES * FEAT;

    prep_weights<<<64, 256, 0, stream>>>(W1, W2, Wl, w1h, w1l, w2h, w2l, wlh, wll);

    const int blocks = (N_NODES + NPB - 1) / NPB;  // 1563
    gnn_layer1<<<blocks, 256, 0, stream>>>(X, nb, w1h, w1l, h1);
    gnn_layer2_final<<<blocks, 256, 0, stream>>>(h1, nb, w2h, w2l, wlh, wll, out);
}

// Round 3
// 343.116 us; speedup vs baseline: 1.2582x; 1.2582x over previous
//
#include <hip/hip_runtime.h>
#include <cstdint>
#include <cstddef>

typedef unsigned short u16;
typedef __bf16 bf16x8 __attribute__((ext_vector_type(8)));
typedef u16 u16x8 __attribute__((ext_vector_type(8)));
typedef float f32x4 __attribute__((ext_vector_type(4)));

#define N_NODES 100000
#define SAMPLE 25
#define FEAT 128
#define CLASSES 40

__device__ __forceinline__ float bf2f(u16 v) {
    return __uint_as_float(((unsigned)v) << 16);
}
__device__ __forceinline__ u16 f2bf(float f) {
    unsigned u = __float_as_uint(f);
    u += 0x7FFFu + ((u >> 16) & 1u);
    return (u16)(u >> 16);
}
__device__ __forceinline__ void split_bf(float x, u16& hi, u16& lo) {
    hi = f2bf(x);
    lo = f2bf(x - bf2f(hi));
}

// split 8 fp32 values into hi/lo bf16 fragments
__device__ __forceinline__ void split8(const float* ap, bf16x8& ah, bf16x8& al) {
    union { u16x8 u; bf16x8 b; } H, L;
    #pragma unroll
    for (int j = 0; j < 8; ++j) {
        u16 h, lo; split_bf(ap[j], h, lo);
        H.u[j] = h; L.u[j] = lo;
    }
    ah = H.b; al = L.b;
}

__device__ __forceinline__ f32x4 mfma_split(bf16x8 ah, bf16x8 al,
                                            bf16x8 bh, bf16x8 bl, f32x4 acc) {
    acc = __builtin_amdgcn_mfma_f32_16x16x32_bf16(ah, bh, acc, 0, 0, 0);
    acc = __builtin_amdgcn_mfma_f32_16x16x32_bf16(al, bh, acc, 0, 0, 0);
    acc = __builtin_amdgcn_mfma_f32_16x16x32_bf16(ah, bl, acc, 0, 0, 0);
    return acc;
}

// ---------------------------------------------------------------------------
// Prep: split fp32 weights into bf16 hi/lo pairs
// ---------------------------------------------------------------------------
__global__ __launch_bounds__(256) void prep_weights(
    const float* __restrict__ W1, const float* __restrict__ W2,
    const float* __restrict__ Wl,
    u16* __restrict__ w1h, u16* __restrict__ w1l,
    u16* __restrict__ w2h, u16* __restrict__ w2l,
    u16* __restrict__ wlh, u16* __restrict__ wll)
{
    const int i = blockIdx.x * 256 + threadIdx.x;
    const int stride = gridDim.x * 256;
    for (int j = i; j < FEAT * FEAT; j += stride) {
        split_bf(W1[j], w1h[j], w1l[j]);
        split_bf(W2[j], w2h[j], w2l[j]);
    }
    for (int j = i; j < CLASSES * FEAT; j += stride) {
        split_bf(Wl[j], wlh[j], wll[j]);
    }
}

// ===========================================================================
// FAST PATH (needs ws >= Z1+Z2+weights): commuted scheme
// ===========================================================================
#define NPB32 32

// K1: Z1 = X @ W1^T  (dense, streamed; bf16 out) — 3125 blocks x 128 thr
__global__ __launch_bounds__(128) void k1_gemm(
    const float* __restrict__ X,
    const u16* __restrict__ w1h, const u16* __restrict__ w1l,
    u16* __restrict__ Z1)
{
    const int t = threadIdx.x;
    const int w  = t >> 6;
    const int l  = t & 63;
    const int lr = l & 15;
    const int lq = l >> 4;
    const int blockStart = blockIdx.x * NPB32;
    const float* Xrow = X + (size_t)(blockStart + w * 16 + lr) * FEAT;

    bf16x8 ah[4], al[4];
    #pragma unroll
    for (int k = 0; k < 4; ++k) {
        f32x4 x0 = *(const f32x4*)(Xrow + k * 32 + lq * 8);
        f32x4 x1 = *(const f32x4*)(Xrow + k * 32 + lq * 8 + 4);
        float tmp[8];
        #pragma unroll
        for (int j = 0; j < 4; ++j) { tmp[j] = x0[j]; tmp[4 + j] = x1[j]; }
        split8(tmp, ah[k], al[k]);
    }

    #pragma unroll
    for (int c = 0; c < 8; ++c) {
        f32x4 acc = {0.f, 0.f, 0.f, 0.f};
        #pragma unroll
        for (int k = 0; k < 4; ++k) {
            const size_t off = (size_t)(c * 16 + lr) * FEAT + k * 32 + lq * 8;
            bf16x8 bh = *(const bf16x8*)(w1h + off);
            bf16x8 bl = *(const bf16x8*)(w1l + off);
            acc = mfma_split(ah[k], al[k], bh, bl, acc);
        }
        #pragma unroll
        for (int r = 0; r < 4; ++r) {
            int node = blockStart + w * 16 + lq * 4 + r;
            Z1[(size_t)node * FEAT + c * 16 + lr] = f2bf(acc[r]);  // no relu
        }
    }
}

// K2: h1 = relu(mean(Z1[nb])); Z2 = h1 @ W2^T (bf16, no relu)
__global__ __launch_bounds__(128) void k2_hop(
    const u16* __restrict__ Zin, const int* __restrict__ nb,
    const u16* __restrict__ wh, const u16* __restrict__ wl,
    u16* __restrict__ Zout)
{
    __shared__ int nbs[NPB32 * SAMPLE];
    __shared__ float agg[NPB32][FEAT + 4];

    const int t = threadIdx.x;
    const int blockStart = blockIdx.x * NPB32;

    for (int i = t; i < NPB32 * SAMPLE; i += 128)
        nbs[i] = nb[blockStart * SAMPLE + i];
    __syncthreads();

    for (int item = t; item < NPB32 * 16; item += 128) {
        const int nl = item >> 4;
        const int fg = item & 15;
        float acc[8];
        #pragma unroll
        for (int j = 0; j < 8; ++j) acc[j] = 0.f;
        const int* myn = &nbs[nl * SAMPLE];
        #pragma unroll 5
        for (int s = 0; s < SAMPLE; ++s) {
            u16x8 v = *(const u16x8*)(Zin + (size_t)myn[s] * FEAT + fg * 8);
            #pragma unroll
            for (int j = 0; j < 8; ++j) acc[j] += bf2f(v[j]);
        }
        #pragma unroll
        for (int j = 0; j < 8; ++j) {
            float m = acc[j] * (1.0f / SAMPLE);
            agg[nl][fg * 8 + j] = m > 0.f ? m : 0.f;   // relu(mean)
        }
    }
    __syncthreads();

    const int w  = t >> 6;
    const int l  = t & 63;
    const int lr = l & 15;
    const int lq = l >> 4;

    bf16x8 ah[4], al[4];
    #pragma unroll
    for (int k = 0; k < 4; ++k)
        split8(&agg[w * 16 + lr][k * 32 + lq * 8], ah[k], al[k]);

    #pragma unroll
    for (int c = 0; c < 8; ++c) {
        f32x4 acc = {0.f, 0.f, 0.f, 0.f};
        #pragma unroll
        for (int k = 0; k < 4; ++k) {
            const size_t off = (size_t)(c * 16 + lr) * FEAT + k * 32 + lq * 8;
            bf16x8 bh = *(const bf16x8*)(wh + off);
            bf16x8 bl = *(const bf16x8*)(wl + off);
            acc = mfma_split(ah[k], al[k], bh, bl, acc);
        }
        #pragma unroll
        for (int r = 0; r < 4; ++r) {
            int node = blockStart + w * 16 + lq * 4 + r;
            Zout[(size_t)node * FEAT + c * 16 + lr] = f2bf(acc[r]);  // no relu
        }
    }
}

// K3: h2 = relu(mean(Z2[nb])); out = h2 @ Wlast^T (fp32)
__global__ __launch_bounds__(128) void k3_hop(
    const u16* __restrict__ Zin, const int* __restrict__ nb,
    const u16* __restrict__ wh, const u16* __restrict__ wl,
    float* __restrict__ out)
{
    __shared__ int nbs[NPB32 * SAMPLE];
    __shared__ float agg[NPB32][FEAT + 4];

    const int t = threadIdx.x;
    const int blockStart = blockIdx.x * NPB32;

    for (int i = t; i < NPB32 * SAMPLE; i += 128)
        nbs[i] = nb[blockStart * SAMPLE + i];
    __syncthreads();

    for (int item = t; item < NPB32 * 16; item += 128) {
        const int nl = item >> 4;
        const int fg = item & 15;
        float acc[8];
        #pragma unroll
        for (int j = 0; j < 8; ++j) acc[j] = 0.f;
        const int* myn = &nbs[nl * SAMPLE];
        #pragma unroll 5
        for (int s = 0; s < SAMPLE; ++s) {
            u16x8 v = *(const u16x8*)(Zin + (size_t)myn[s] * FEAT + fg * 8);
            #pragma unroll
            for (int j = 0; j < 8; ++j) acc[j] += bf2f(v[j]);
        }
        #pragma unroll
        for (int j = 0; j < 8; ++j) {
            float m = acc[j] * (1.0f / SAMPLE);
            agg[nl][fg * 8 + j] = m > 0.f ? m : 0.f;   // relu(mean)
        }
    }
    __syncthreads();

    const int w  = t >> 6;
    const int l  = t & 63;
    const int lr = l & 15;
    const int lq = l >> 4;

    bf16x8 ah[4], al[4];
    #pragma unroll
    for (int k = 0; k < 4; ++k)
        split8(&agg[w * 16 + lr][k * 32 + lq * 8], ah[k], al[k]);

    #pragma unroll
    for (int c = 0; c < 3; ++c) {
        const int o = c * 16 + lr;
        f32x4 acc = {0.f, 0.f, 0.f, 0.f};
        #pragma unroll
        for (int k = 0; k < 4; ++k) {
            bf16x8 bh, bl;
            if (o < CLASSES) {
                const size_t off = (size_t)o * FEAT + k * 32 + lq * 8;
                bh = *(const bf16x8*)(wh + off);
                bl = *(const bf16x8*)(wl + off);
            } else {
                #pragma unroll
                for (int j = 0; j < 8; ++j) { bh[j] = (__bf16)0.f; bl[j] = (__bf16)0.f; }
            }
            acc = mfma_split(ah[k], al[k], bh, bl, acc);
        }
        if (o < CLASSES) {
            #pragma unroll
            for (int r = 0; r < 4; ++r) {
                int node = blockStart + w * 16 + lq * 4 + r;
                out[(size_t)node * CLASSES + o] = acc[r];
            }
        }
    }
}

// ===========================================================================
// FALLBACK PATH (proven R2 kernels, ws >= 25.9 MB only)
// ===========================================================================
#define NPB 64
#define AGG_STRIDE 136

__global__ __launch_bounds__(256) void gnn_layer1(
    const float* __restrict__ X, const int* __restrict__ nb,
    const u16* __restrict__ w1h, const u16* __restrict__ w1l,
    u16* __restrict__ h1)
{
    __shared__ int nbs[NPB * SAMPLE];
    __shared__ u16 agg_h[NPB][AGG_STRIDE];
    __shared__ u16 agg_l[NPB][AGG_STRIDE];

    const int t = threadIdx.x;
    const int blockStart = blockIdx.x * NPB;

    for (int i = t; i < NPB * SAMPLE; i += 256) {
        int gi = blockStart * SAMPLE + i;
        if (gi >= N_NODES * SAMPLE) gi = N_NODES * SAMPLE - 1;
        nbs[i] = nb[gi];
    }
    __syncthreads();

    for (int item = t; item < NPB * 16; item += 256) {
        const int nl = item >> 4;
        const int fg = item & 15;
        float acc[8];
        #pragma unroll
        for (int j = 0; j < 8; ++j) acc[j] = 0.f;
        const int* myn = &nbs[nl * SAMPLE];
        for (int s = 0; s < SAMPLE; ++s) {
            const float4* p = (const float4*)(X + (size_t)myn[s] * FEAT + fg * 8);
            float4 a = p[0], b = p[1];
            acc[0] += a.x; acc[1] += a.y; acc[2] += a.z; acc[3] += a.w;
            acc[4] += b.x; acc[5] += b.y; acc[6] += b.z; acc[7] += b.w;
        }
        u16x8 oh, ol;
        #pragma unroll
        for (int j = 0; j < 8; ++j) {
            float m = acc[j] * (1.0f / SAMPLE);
            u16 h, lo; split_bf(m, h, lo);
            oh[j] = h; ol[j] = lo;
        }
        *(u16x8*)&agg_h[nl][fg * 8] = oh;
        *(u16x8*)&agg_l[nl][fg * 8] = ol;
    }
    __syncthreads();

    const int w  = t >> 6;
    const int l  = t & 63;
    const int lr = l & 15;
    const int lq = l >> 4;

    bf16x8 ah[4], al[4];
    #pragma unroll
    for (int k = 0; k < 4; ++k) {
        ah[k] = *(const bf16x8*)&agg_h[w * 16 + lr][k * 32 + lq * 8];
        al[k] = *(const bf16x8*)&agg_l[w * 16 + lr][k * 32 + lq * 8];
    }

    #pragma unroll
    for (int c = 0; c < 8; ++c) {
        f32x4 acc = {0.f, 0.f, 0.f, 0.f};
        #pragma unroll
        for (int k = 0; k < 4; ++k) {
            const size_t off = (size_t)(c * 16 + lr) * FEAT + k * 32 + lq * 8;
            bf16x8 bh = *(const bf16x8*)(w1h + off);
            bf16x8 bl = *(const bf16x8*)(w1l + off);
            acc = mfma_split(ah[k], al[k], bh, bl, acc);
        }
        #pragma unroll
        for (int r = 0; r < 4; ++r) {
            int node = blockStart + w * 16 + lq * 4 + r;
            if (node < N_NODES) {
                float v = acc[r] > 0.f ? acc[r] : 0.f;
                h1[(size_t)node * FEAT + c * 16 + lr] = f2bf(v);
            }
        }
    }
}

__global__ __launch_bounds__(256) void gnn_layer2_final(
    const u16* __restrict__ h1, const int* __restrict__ nb,
    const u16* __restrict__ w2h, const u16* __restrict__ w2l,
    const u16* __restrict__ wlh, const u16* __restrict__ wll,
    float* __restrict__ out)
{
    __shared__ int nbs[NPB * SAMPLE];
    __shared__ u16 agg_h[NPB][AGG_STRIDE];
    __shared__ u16 agg_l[NPB][AGG_STRIDE];

    const int t = threadIdx.x;
    const int blockStart = blockIdx.x * NPB;

    for (int i = t; i < NPB * SAMPLE; i += 256) {
        int gi = blockStart * SAMPLE + i;
        if (gi >= N_NODES * SAMPLE) gi = N_NODES * SAMPLE - 1;
        nbs[i] = nb[gi];
    }
    __syncthreads();

    for (int item = t; item < NPB * 16; item += 256) {
        const int nl = item >> 4;
        const int fg = item & 15;
        float acc[8];
        #pragma unroll
        for (int j = 0; j < 8; ++j) acc[j] = 0.f;
        const int* myn = &nbs[nl * SAMPLE];
        for (int s = 0; s < SAMPLE; ++s) {
            u16x8 v = *(const u16x8*)(h1 + (size_t)myn[s] * FEAT + fg * 8);
            #pragma unroll
            for (int j = 0; j < 8; ++j) acc[j] += bf2f(v[j]);
        }
        u16x8 oh, ol;
        #pragma unroll
        for (int j = 0; j < 8; ++j) {
            float m = acc[j] * (1.0f / SAMPLE);
            u16 h, lo; split_bf(m, h, lo);
            oh[j] = h; ol[j] = lo;
        }
        *(u16x8*)&agg_h[nl][fg * 8] = oh;
        *(u16x8*)&agg_l[nl][fg * 8] = ol;
    }
    __syncthreads();

    const int w  = t >> 6;
    const int l  = t & 63;
    const int lr = l & 15;
    const int lq = l >> 4;

    f32x4 hacc[8];
    {
        bf16x8 ah[4], al[4];
        #pragma unroll
        for (int k = 0; k < 4; ++k) {
            ah[k] = *(const bf16x8*)&agg_h[w * 16 + lr][k * 32 + lq * 8];
            al[k] = *(const bf16x8*)&agg_l[w * 16 + lr][k * 32 + lq * 8];
        }
        #pragma unroll
        for (int c = 0; c < 8; ++c) {
            f32x4 acc = {0.f, 0.f, 0.f, 0.f};
            #pragma unroll
            for (int k = 0; k < 4; ++k) {
                const size_t off = (size_t)(c * 16 + lr) * FEAT + k * 32 + lq * 8;
                bf16x8 bh = *(const bf16x8*)(w2h + off);
                bf16x8 bl = *(const bf16x8*)(w2l + off);
                acc = mfma_split(ah[k], al[k], bh, bl, acc);
            }
            hacc[c] = acc;
        }
    }
    __syncthreads();

    #pragma unroll
    for (int c = 0; c < 8; ++c) {
        #pragma unroll
        for (int r = 0; r < 4; ++r) {
            float v = hacc[c][r] > 0.f ? hacc[c][r] : 0.f;
            u16 h, l2; split_bf(v, h, l2);
            agg_h[w * 16 + lq * 4 + r][c * 16 + lr] = h;
            agg_l[w * 16 + lq * 4 + r][c * 16 + lr] = l2;
        }
    }
    __syncthreads();

    {
        bf16x8 ah[4], al[4];
        #pragma unroll
        for (int k = 0; k < 4; ++k) {
            ah[k] = *(const bf16x8*)&agg_h[w * 16 + lr][k * 32 + lq * 8];
            al[k] = *(const bf16x8*)&agg_l[w * 16 + lr][k * 32 + lq * 8];
        }
        #pragma unroll
        for (int c = 0; c < 3; ++c) {
            const int o = c * 16 + lr;
            f32x4 acc = {0.f, 0.f, 0.f, 0.f};
            #pragma unroll
            for (int k = 0; k < 4; ++k) {
                bf16x8 bh, bl;
                if (o < CLASSES) {
                    const size_t off = (size_t)o * FEAT + k * 32 + lq * 8;
                    bh = *(const bf16x8*)(wlh + off);
                    bl = *(const bf16x8*)(wll + off);
                } else {
                    #pragma unroll
                    for (int j = 0; j < 8; ++j) { bh[j] = (__bf16)0.f; bl[j] = (__bf16)0.f; }
                }
                acc = mfma_split(ah[k], al[k], bh, bl, acc);
            }
            if (o < CLASSES) {
                #pragma unroll
                for (int r = 0; r < 4; ++r) {
                    int node = blockStart + w * 16 + lq * 4 + r;
                    if (node < N_NODES) {
                        out[(size_t)node * CLASSES + o] = acc[r];
                    }
                }
            }
        }
    }
}

extern "C" void kernel_launch(void* const* d_in, const int* in_sizes, int n_in,
                              void* d_out, int out_size, void* d_ws, size_t ws_size,
                              hipStream_t stream) {
    const float* X  = (const float*)d_in[0];
    const int*   nb = (const int*)d_in[1];
    const float* W1 = (const float*)d_in[2];
    const float* W2 = (const float*)d_in[3];
    const float* Wl = (const float*)d_in[4];
    float* out = (float*)d_out;

    const size_t zelems = (size_t)N_NODES * FEAT;                 // 12.8M
    const size_t welems = 4 * (size_t)FEAT * FEAT + 2 * (size_t)CLASSES * FEAT;
    const size_t need_fast = (2 * zelems + welems) * sizeof(u16); // ~51.4 MB

    if (ws_size >= need_fast) {
        // fast path: commuted GEMM-then-gather
        u16* Z1  = (u16*)d_ws;
        u16* Z2  = Z1 + zelems;
        u16* w1h = Z2 + zelems;
        u16* w1l = w1h + FEAT * FEAT;
        u16* w2h = w1l + FEAT * FEAT;
        u16* w2l = w2h + FEAT * FEAT;
        u16* wlh = w2l + FEAT * FEAT;
        u16* wll = wlh + CLASSES * FEAT;

        prep_weights<<<64, 256, 0, stream>>>(W1, W2, Wl, w1h, w1l, w2h, w2l, wlh, wll);
        const int blocks = N_NODES / NPB32;  // 3125, exact
        k1_gemm<<<blocks, 128, 0, stream>>>(X, w1h, w1l, Z1);
        k2_hop<<<blocks, 128, 0, stream>>>(Z1, nb, w2h, w2l, Z2);
        k3_hop<<<blocks, 128, 0, stream>>>(Z2, nb, wlh, wll, out);
    } else {
        // fallback: proven R2 path (needs ~25.9 MB)
        u16* h1  = (u16*)d_ws;
        u16* w1h = h1 + zelems;
        u16* w1l = w1h + FEAT * FEAT;
        u16* w2h = w1l + FEAT * FEAT;
        u16* w2l = w2h + FEAT * FEAT;
        u16* wlh = w2l + FEAT * FEAT;
        u16* wll = wlh + CLASSES * FEAT;

        prep_weights<<<64, 256, 0, stream>>>(W1, W2, Wl, w1h, w1l, w2h, w2l, wlh, wll);
        const int blocks = (N_NODES + NPB - 1) / NPB;  // 1563
        gnn_layer1<<<blocks, 256, 0, stream>>>(X, nb, w1h, w1l, h1);
        gnn_layer2_final<<<blocks, 256, 0, stream>>>(h1, nb, w2h, w2l, wlh, wll, out);
    }
}

// Round 4
// 328.618 us; speedup vs baseline: 1.3137x; 1.0441x over previous
//
#include <hip/hip_runtime.h>
#include <cstdint>
#include <cstddef>

typedef unsigned short u16;
typedef __bf16 bf16x8 __attribute__((ext_vector_type(8)));
typedef u16 u16x8 __attribute__((ext_vector_type(8)));
typedef float f32x4 __attribute__((ext_vector_type(4)));

#define N_NODES 100000
#define SAMPLE 25
#define FEAT 128
#define CLASSES 40

__device__ __forceinline__ float bf2f(u16 v) {
    return __uint_as_float(((unsigned)v) << 16);
}
__device__ __forceinline__ u16 f2bf(float f) {
    unsigned u = __float_as_uint(f);
    u += 0x7FFFu + ((u >> 16) & 1u);
    return (u16)(u >> 16);
}
__device__ __forceinline__ void split_bf(float x, u16& hi, u16& lo) {
    hi = f2bf(x);
    lo = f2bf(x - bf2f(hi));
}

__device__ __forceinline__ void split8(const float* ap, bf16x8& ah, bf16x8& al) {
    union { u16x8 u; bf16x8 b; } H, L;
    #pragma unroll
    for (int j = 0; j < 8; ++j) {
        u16 h, lo; split_bf(ap[j], h, lo);
        H.u[j] = h; L.u[j] = lo;
    }
    ah = H.b; al = L.b;
}

__device__ __forceinline__ f32x4 mfma_split(bf16x8 ah, bf16x8 al,
                                            bf16x8 bh, bf16x8 bl, f32x4 acc) {
    acc = __builtin_amdgcn_mfma_f32_16x16x32_bf16(ah, bh, acc, 0, 0, 0);
    acc = __builtin_amdgcn_mfma_f32_16x16x32_bf16(al, bh, acc, 0, 0, 0);
    acc = __builtin_amdgcn_mfma_f32_16x16x32_bf16(ah, bl, acc, 0, 0, 0);
    return acc;
}

// ---------------------------------------------------------------------------
// Prep: split fp32 weights into bf16 hi/lo pairs
// ---------------------------------------------------------------------------
__global__ __launch_bounds__(256) void prep_weights(
    const float* __restrict__ W1, const float* __restrict__ W2,
    const float* __restrict__ Wl,
    u16* __restrict__ w1h, u16* __restrict__ w1l,
    u16* __restrict__ w2h, u16* __restrict__ w2l,
    u16* __restrict__ wlh, u16* __restrict__ wll)
{
    const int i = blockIdx.x * 256 + threadIdx.x;
    const int stride = gridDim.x * 256;
    for (int j = i; j < FEAT * FEAT; j += stride) {
        split_bf(W1[j], w1h[j], w1l[j]);
        split_bf(W2[j], w2h[j], w2l[j]);
    }
    for (int j = i; j < CLASSES * FEAT; j += stride) {
        split_bf(Wl[j], wlh[j], wll[j]);
    }
}

// ===========================================================================
// FAST PATH: commuted scheme (Z1 = X@W1^T first, then gather bf16 rows)
// ===========================================================================
#define NPB32 32
#define ZT_STRIDE 136

// K1: Z1 = X @ W1^T  (dense streamed GEMM, bf16 out, LDS-staged stores)
__global__ __launch_bounds__(128, 4) void k1_gemm(
    const float* __restrict__ X,
    const u16* __restrict__ w1h, const u16* __restrict__ w1l,
    u16* __restrict__ Z1)
{
    __shared__ u16 zt[NPB32][ZT_STRIDE];   // 8.7 KB

    const int t = threadIdx.x;
    const int w  = t >> 6;
    const int l  = t & 63;
    const int lr = l & 15;
    const int lq = l >> 4;
    const int blockStart = blockIdx.x * NPB32;
    const float* Xrow = X + (size_t)(blockStart + w * 16 + lr) * FEAT;

    bf16x8 ah[4], al[4];
    #pragma unroll
    for (int k = 0; k < 4; ++k) {
        f32x4 x0 = *(const f32x4*)(Xrow + k * 32 + lq * 8);
        f32x4 x1 = *(const f32x4*)(Xrow + k * 32 + lq * 8 + 4);
        float tmp[8];
        #pragma unroll
        for (int j = 0; j < 4; ++j) { tmp[j] = x0[j]; tmp[4 + j] = x1[j]; }
        split8(tmp, ah[k], al[k]);
    }

    #pragma unroll
    for (int c = 0; c < 8; ++c) {
        f32x4 acc = {0.f, 0.f, 0.f, 0.f};
        #pragma unroll
        for (int k = 0; k < 4; ++k) {
            const size_t off = (size_t)(c * 16 + lr) * FEAT + k * 32 + lq * 8;
            bf16x8 bh = *(const bf16x8*)(w1h + off);
            bf16x8 bl = *(const bf16x8*)(w1l + off);
            acc = mfma_split(ah[k], al[k], bh, bl, acc);
        }
        #pragma unroll
        for (int r = 0; r < 4; ++r)
            zt[w * 16 + lq * 4 + r][c * 16 + lr] = f2bf(acc[r]);  // no relu
    }
    __syncthreads();

    // coalesced 16B stores: 32 rows x 128 u16
    #pragma unroll
    for (int p = 0; p < 4; ++p) {
        const int idx = p * 128 + t;
        const int row = idx >> 4;
        const int col = (idx & 15) * 8;
        *(u16x8*)(Z1 + (size_t)(blockStart + row) * FEAT + col) =
            *(const u16x8*)&zt[row][col];
    }
}

// K2: h1 = relu(mean(Z1[nb])); Z2 = h1 @ W2^T (bf16, LDS-staged stores)
__global__ __launch_bounds__(128, 3) void k2_hop(
    const u16* __restrict__ Zin, const int* __restrict__ nb,
    const u16* __restrict__ wh, const u16* __restrict__ wl,
    u16* __restrict__ Zout)
{
    __shared__ int nbs[NPB32 * SAMPLE];
    __shared__ float agg[NPB32][132];      // 16.9 KB, reused as zt later

    const int t = threadIdx.x;
    const int blockStart = blockIdx.x * NPB32;

    for (int i = t; i < NPB32 * SAMPLE; i += 128)
        nbs[i] = nb[blockStart * SAMPLE + i];
    __syncthreads();

    // gather: burst all 25 loads into registers, then accumulate
    #pragma unroll 1
    for (int it = 0; it < 4; ++it) {
        const int item = t + it * 128;
        const int nl = item >> 4;
        const int fg = item & 15;
        const int* myn = &nbs[nl * SAMPLE];
        u16x8 buf[SAMPLE];
        #pragma unroll
        for (int s = 0; s < SAMPLE; ++s)
            buf[s] = *(const u16x8*)(Zin + ((size_t)myn[s] << 7) + fg * 8);
        float acc[8];
        #pragma unroll
        for (int j = 0; j < 8; ++j) acc[j] = 0.f;
        #pragma unroll
        for (int s = 0; s < SAMPLE; ++s) {
            #pragma unroll
            for (int j = 0; j < 8; ++j) acc[j] += bf2f(buf[s][j]);
        }
        #pragma unroll
        for (int j = 0; j < 8; ++j) {
            float m = acc[j] * (1.0f / SAMPLE);
            agg[nl][fg * 8 + j] = m > 0.f ? m : 0.f;   // relu(mean)
        }
    }
    __syncthreads();

    const int w  = t >> 6;
    const int l  = t & 63;
    const int lr = l & 15;
    const int lq = l >> 4;

    bf16x8 ah[4], al[4];
    #pragma unroll
    for (int k = 0; k < 4; ++k)
        split8(&agg[w * 16 + lr][k * 32 + lq * 8], ah[k], al[k]);
    __syncthreads();                        // A-frags in regs; agg reusable

    u16* zt = (u16*)agg;                    // [NPB32][ZT_STRIDE] u16 view

    #pragma unroll
    for (int c = 0; c < 8; ++c) {
        f32x4 acc = {0.f, 0.f, 0.f, 0.f};
        #pragma unroll
        for (int k = 0; k < 4; ++k) {
            const size_t off = (size_t)(c * 16 + lr) * FEAT + k * 32 + lq * 8;
            bf16x8 bh = *(const bf16x8*)(wh + off);
            bf16x8 bl = *(const bf16x8*)(wl + off);
            acc = mfma_split(ah[k], al[k], bh, bl, acc);
        }
        #pragma unroll
        for (int r = 0; r < 4; ++r)
            zt[(size_t)(w * 16 + lq * 4 + r) * ZT_STRIDE + c * 16 + lr] = f2bf(acc[r]);
    }
    __syncthreads();

    #pragma unroll
    for (int p = 0; p < 4; ++p) {
        const int idx = p * 128 + t;
        const int row = idx >> 4;
        const int col = (idx & 15) * 8;
        *(u16x8*)(Zout + (size_t)(blockStart + row) * FEAT + col) =
            *(const u16x8*)&zt[(size_t)row * ZT_STRIDE + col];
    }
}

// K3: h2 = relu(mean(Z2[nb])); out = h2 @ Wlast^T (fp32, direct stores)
__global__ __launch_bounds__(128, 3) void k3_hop(
    const u16* __restrict__ Zin, const int* __restrict__ nb,
    const u16* __restrict__ wh, const u16* __restrict__ wl,
    float* __restrict__ out)
{
    __shared__ int nbs[NPB32 * SAMPLE];
    __shared__ float agg[NPB32][132];

    const int t = threadIdx.x;
    const int blockStart = blockIdx.x * NPB32;

    for (int i = t; i < NPB32 * SAMPLE; i += 128)
        nbs[i] = nb[blockStart * SAMPLE + i];
    __syncthreads();

    #pragma unroll 1
    for (int it = 0; it < 4; ++it) {
        const int item = t + it * 128;
        const int nl = item >> 4;
        const int fg = item & 15;
        const int* myn = &nbs[nl * SAMPLE];
        u16x8 buf[SAMPLE];
        #pragma unroll
        for (int s = 0; s < SAMPLE; ++s)
            buf[s] = *(const u16x8*)(Zin + ((size_t)myn[s] << 7) + fg * 8);
        float acc[8];
        #pragma unroll
        for (int j = 0; j < 8; ++j) acc[j] = 0.f;
        #pragma unroll
        for (int s = 0; s < SAMPLE; ++s) {
            #pragma unroll
            for (int j = 0; j < 8; ++j) acc[j] += bf2f(buf[s][j]);
        }
        #pragma unroll
        for (int j = 0; j < 8; ++j) {
            float m = acc[j] * (1.0f / SAMPLE);
            agg[nl][fg * 8 + j] = m > 0.f ? m : 0.f;   // relu(mean)
        }
    }
    __syncthreads();

    const int w  = t >> 6;
    const int l  = t & 63;
    const int lr = l & 15;
    const int lq = l >> 4;

    bf16x8 ah[4], al[4];
    #pragma unroll
    for (int k = 0; k < 4; ++k)
        split8(&agg[w * 16 + lr][k * 32 + lq * 8], ah[k], al[k]);

    #pragma unroll
    for (int c = 0; c < 3; ++c) {
        const int o = c * 16 + lr;
        f32x4 acc = {0.f, 0.f, 0.f, 0.f};
        #pragma unroll
        for (int k = 0; k < 4; ++k) {
            bf16x8 bh, bl;
            if (o < CLASSES) {
                const size_t off = (size_t)o * FEAT + k * 32 + lq * 8;
                bh = *(const bf16x8*)(wh + off);
                bl = *(const bf16x8*)(wl + off);
            } else {
                #pragma unroll
                for (int j = 0; j < 8; ++j) { bh[j] = (__bf16)0.f; bl[j] = (__bf16)0.f; }
            }
            acc = mfma_split(ah[k], al[k], bh, bl, acc);
        }
        if (o < CLASSES) {
            #pragma unroll
            for (int r = 0; r < 4; ++r) {
                const int node = blockStart + w * 16 + lq * 4 + r;
                out[(size_t)node * CLASSES + o] = acc[r];
            }
        }
    }
}

// ===========================================================================
// FALLBACK PATH (proven R2 kernels, ws >= 25.9 MB only)
// ===========================================================================
#define NPB 64
#define AGG_STRIDE 136

__global__ __launch_bounds__(256) void gnn_layer1(
    const float* __restrict__ X, const int* __restrict__ nb,
    const u16* __restrict__ w1h, const u16* __restrict__ w1l,
    u16* __restrict__ h1)
{
    __shared__ int nbs[NPB * SAMPLE];
    __shared__ u16 agg_h[NPB][AGG_STRIDE];
    __shared__ u16 agg_l[NPB][AGG_STRIDE];

    const int t = threadIdx.x;
    const int blockStart = blockIdx.x * NPB;

    for (int i = t; i < NPB * SAMPLE; i += 256) {
        int gi = blockStart * SAMPLE + i;
        if (gi >= N_NODES * SAMPLE) gi = N_NODES * SAMPLE - 1;
        nbs[i] = nb[gi];
    }
    __syncthreads();

    for (int item = t; item < NPB * 16; item += 256) {
        const int nl = item >> 4;
        const int fg = item & 15;
        float acc[8];
        #pragma unroll
        for (int j = 0; j < 8; ++j) acc[j] = 0.f;
        const int* myn = &nbs[nl * SAMPLE];
        for (int s = 0; s < SAMPLE; ++s) {
            const float4* p = (const float4*)(X + (size_t)myn[s] * FEAT + fg * 8);
            float4 a = p[0], b = p[1];
            acc[0] += a.x; acc[1] += a.y; acc[2] += a.z; acc[3] += a.w;
            acc[4] += b.x; acc[5] += b.y; acc[6] += b.z; acc[7] += b.w;
        }
        u16x8 oh, ol;
        #pragma unroll
        for (int j = 0; j < 8; ++j) {
            float m = acc[j] * (1.0f / SAMPLE);
            u16 h, lo; split_bf(m, h, lo);
            oh[j] = h; ol[j] = lo;
        }
        *(u16x8*)&agg_h[nl][fg * 8] = oh;
        *(u16x8*)&agg_l[nl][fg * 8] = ol;
    }
    __syncthreads();

    const int w  = t >> 6;
    const int l  = t & 63;
    const int lr = l & 15;
    const int lq = l >> 4;

    bf16x8 ah[4], al[4];
    #pragma unroll
    for (int k = 0; k < 4; ++k) {
        ah[k] = *(const bf16x8*)&agg_h[w * 16 + lr][k * 32 + lq * 8];
        al[k] = *(const bf16x8*)&agg_l[w * 16 + lr][k * 32 + lq * 8];
    }

    #pragma unroll
    for (int c = 0; c < 8; ++c) {
        f32x4 acc = {0.f, 0.f, 0.f, 0.f};
        #pragma unroll
        for (int k = 0; k < 4; ++k) {
            const size_t off = (size_t)(c * 16 + lr) * FEAT + k * 32 + lq * 8;
            bf16x8 bh = *(const bf16x8*)(w1h + off);
            bf16x8 bl = *(const bf16x8*)(w1l + off);
            acc = mfma_split(ah[k], al[k], bh, bl, acc);
        }
        #pragma unroll
        for (int r = 0; r < 4; ++r) {
            int node = blockStart + w * 16 + lq * 4 + r;
            if (node < N_NODES) {
                float v = acc[r] > 0.f ? acc[r] : 0.f;
                h1[(size_t)node * FEAT + c * 16 + lr] = f2bf(v);
            }
        }
    }
}

__global__ __launch_bounds__(256) void gnn_layer2_final(
    const u16* __restrict__ h1, const int* __restrict__ nb,
    const u16* __restrict__ w2h, const u16* __restrict__ w2l,
    const u16* __restrict__ wlh, const u16* __restrict__ wll,
    float* __restrict__ out)
{
    __shared__ int nbs[NPB * SAMPLE];
    __shared__ u16 agg_h[NPB][AGG_STRIDE];
    __shared__ u16 agg_l[NPB][AGG_STRIDE];

    const int t = threadIdx.x;
    const int blockStart = blockIdx.x * NPB;

    for (int i = t; i < NPB * SAMPLE; i += 256) {
        int gi = blockStart * SAMPLE + i;
        if (gi >= N_NODES * SAMPLE) gi = N_NODES * SAMPLE - 1;
        nbs[i] = nb[gi];
    }
    __syncthreads();

    for (int item = t; item < NPB * 16; item += 256) {
        const int nl = item >> 4;
        const int fg = item & 15;
        float acc[8];
        #pragma unroll
        for (int j = 0; j < 8; ++j) acc[j] = 0.f;
        const int* myn = &nbs[nl * SAMPLE];
        for (int s = 0; s < SAMPLE; ++s) {
            u16x8 v = *(const u16x8*)(h1 + (size_t)myn[s] * FEAT + fg * 8);
            #pragma unroll
            for (int j = 0; j < 8; ++j) acc[j] += bf2f(v[j]);
        }
        u16x8 oh, ol;
        #pragma unroll
        for (int j = 0; j < 8; ++j) {
            float m = acc[j] * (1.0f / SAMPLE);
            u16 h, lo; split_bf(m, h, lo);
            oh[j] = h; ol[j] = lo;
        }
        *(u16x8*)&agg_h[nl][fg * 8] = oh;
        *(u16x8*)&agg_l[nl][fg * 8] = ol;
    }
    __syncthreads();

    const int w  = t >> 6;
    const int l  = t & 63;
    const int lr = l & 15;
    const int lq = l >> 4;

    f32x4 hacc[8];
    {
        bf16x8 ah[4], al[4];
        #pragma unroll
        for (int k = 0; k < 4; ++k) {
            ah[k] = *(const bf16x8*)&agg_h[w * 16 + lr][k * 32 + lq * 8];
            al[k] = *(const bf16x8*)&agg_l[w * 16 + lr][k * 32 + lq * 8];
        }
        #pragma unroll
        for (int c = 0; c < 8; ++c) {
            f32x4 acc = {0.f, 0.f, 0.f, 0.f};
            #pragma unroll
            for (int k = 0; k < 4; ++k) {
                const size_t off = (size_t)(c * 16 + lr) * FEAT + k * 32 + lq * 8;
                bf16x8 bh = *(const bf16x8*)(w2h + off);
                bf16x8 bl = *(const bf16x8*)(w2l + off);
                acc = mfma_split(ah[k], al[k], bh, bl, acc);
            }
            hacc[c] = acc;
        }
    }
    __syncthreads();

    #pragma unroll
    for (int c = 0; c < 8; ++c) {
        #pragma unroll
        for (int r = 0; r < 4; ++r) {
            float v = hacc[c][r] > 0.f ? hacc[c][r] : 0.f;
            u16 h, l2; split_bf(v, h, l2);
            agg_h[w * 16 + lq * 4 + r][c * 16 + lr] = h;
            agg_l[w * 16 + lq * 4 + r][c * 16 + lr] = l2;
        }
    }
    __syncthreads();

    {
        bf16x8 ah[4], al[4];
        #pragma unroll
        for (int k = 0; k < 4; ++k) {
            ah[k] = *(const bf16x8*)&agg_h[w * 16 + lr][k * 32 + lq * 8];
            al[k] = *(const bf16x8*)&agg_l[w * 16 + lr][k * 32 + lq * 8];
        }
        #pragma unroll
        for (int c = 0; c < 3; ++c) {
            const int o = c * 16 + lr;
            f32x4 acc = {0.f, 0.f, 0.f, 0.f};
            #pragma unroll
            for (int k = 0; k < 4; ++k) {
                bf16x8 bh, bl;
                if (o < CLASSES) {
                    const size_t off = (size_t)o * FEAT + k * 32 + lq * 8;
                    bh = *(const bf16x8*)(wlh + off);
                    bl = *(const bf16x8*)(wll + off);
                } else {
                    #pragma unroll
                    for (int j = 0; j < 8; ++j) { bh[j] = (__bf16)0.f; bl[j] = (__bf16)0.f; }
                }
                acc = mfma_split(ah[k], al[k], bh, bl, acc);
            }
            if (o < CLASSES) {
                #pragma unroll
                for (int r = 0; r < 4; ++r) {
                    int node = blockStart + w * 16 + lq * 4 + r;
                    if (node < N_NODES) {
                        out[(size_t)node * CLASSES + o] = acc[r];
                    }
                }
            }
        }
    }
}

extern "C" void kernel_launch(void* const* d_in, const int* in_sizes, int n_in,
                              void* d_out, int out_size, void* d_ws, size_t ws_size,
                              hipStream_t stream) {
    const float* X  = (const float*)d_in[0];
    const int*   nb = (const int*)d_in[1];
    const float* W1 = (const float*)d_in[2];
    const float* W2 = (const float*)d_in[3];
    const float* Wl = (const float*)d_in[4];
    float* out = (float*)d_out;

    const size_t zelems = (size_t)N_NODES * FEAT;                 // 12.8M
    const size_t welems = 4 * (size_t)FEAT * FEAT + 2 * (size_t)CLASSES * FEAT;
    const size_t need_fast = (2 * zelems + welems) * sizeof(u16); // ~51.4 MB

    if (ws_size >= need_fast) {
        u16* Z1  = (u16*)d_ws;
        u16* Z2  = Z1 + zelems;
        u16* w1h = Z2 + zelems;
        u16* w1l = w1h + FEAT * FEAT;
        u16* w2h = w1l + FEAT * FEAT;
        u16* w2l = w2h + FEAT * FEAT;
        u16* wlh = w2l + FEAT * FEAT;
        u16* wll = wlh + CLASSES * FEAT;

        prep_weights<<<64, 256, 0, stream>>>(W1, W2, Wl, w1h, w1l, w2h, w2l, wlh, wll);
        const int blocks = N_NODES / NPB32;  // 3125, exact
        k1_gemm<<<blocks, 128, 0, stream>>>(X, w1h, w1l, Z1);
        k2_hop<<<blocks, 128, 0, stream>>>(Z1, nb, w2h, w2l, Z2);
        k3_hop<<<blocks, 128, 0, stream>>>(Z2, nb, wlh, wll, out);
    } else {
        u16* h1  = (u16*)d_ws;
        u16* w1h = h1 + zelems;
        u16* w1l = w1h + FEAT * FEAT;
        u16* w2h = w1l + FEAT * FEAT;
        u16* w2l = w2h + FEAT * FEAT;
        u16* wlh = w2l + FEAT * FEAT;
        u16* wll = wlh + CLASSES * FEAT;

        prep_weights<<<64, 256, 0, stream>>>(W1, W2, Wl, w1h, w1l, w2h, w2l, wlh, wll);
        const int blocks = (N_NODES + NPB - 1) / NPB;  // 1563
        gnn_layer1<<<blocks, 256, 0, stream>>>(X, nb, w1h, w1l, h1);
        gnn_layer2_final<<<blocks, 256, 0, stream>>>(h1, nb, w2h, w2l, wlh, wll, out);
    }
}